// Round 7
// baseline (201.464 us; speedup 1.0000x reference)
//
#include <hip/hip_runtime.h>
#include <cstdint>
#include <cstddef>

typedef __bf16 bf16;
typedef __bf16 bf16x8 __attribute__((ext_vector_type(8)));
typedef __bf16 bf16x4v __attribute__((ext_vector_type(4)));
typedef float  f32x4  __attribute__((ext_vector_type(4)));

#define MFMA(a, b, c) __builtin_amdgcn_mfma_f32_16x16x32_bf16((a), (b), (c), 0, 0, 0)

typedef __attribute__((address_space(3))) unsigned int  lds_u32;
typedef __attribute__((address_space(1))) unsigned int glob_u32;

// B=4, N=1024, DIM=768, HEADS=12, DIM_HEAD=64, INNER=768
// c2 = 0.5/sqrt(768)*log2(e) is folded into qcat by k_gemm12's epilogue.

// ---------------------------------------------------------------------------
// fp32 -> bf16 convert for x and pos in one launch. grid 6144 x 256.
// ---------------------------------------------------------------------------
__global__ void k_cvt2(const float* __restrict__ x, const float* __restrict__ pos,
                       bf16* __restrict__ xb, bf16* __restrict__ posb) {
    int i = blockIdx.x * 256 + threadIdx.x;
    const float* in = x; bf16* out = xb;
    if (i >= 786432) { i -= 786432; in = pos; out = posb; }
    float4 v = reinterpret_cast<const float4*>(in)[i];
    bf16x4v o; o[0] = (bf16)v.x; o[1] = (bf16)v.y; o[2] = (bf16)v.z; o[3] = (bf16)v.w;
    reinterpret_cast<bf16x4v*>(out)[i] = o;
}

// ---------------------------------------------------------------------------
// Transposing convert for all 3 weights in one launch: in[k][n] fp32 (k=768)
// -> out[n][768] bf16. grid (144, 24) x 256.
// ---------------------------------------------------------------------------
__global__ void k_tr(const float* __restrict__ w_qkv, const float* __restrict__ w_qk_pos,
                     const float* __restrict__ w_out,
                     bf16* __restrict__ wqkvT, bf16* __restrict__ wqkposT,
                     bf16* __restrict__ woutT) {
    __shared__ float t[32][33];
    int bx = blockIdx.x;
    const float* in; bf16* out; int N;
    if (bx < 72)       { in = w_qkv;    out = wqkvT;   N = 2304; }
    else if (bx < 120) { in = w_qk_pos; out = wqkposT; N = 1536; bx -= 72; }
    else               { in = w_out;    out = woutT;   N = 768;  bx -= 120; }
    const int n0 = bx * 32, k0 = blockIdx.y * 32;
    const int tx = threadIdx.x & 31, ty = threadIdx.x >> 5;
#pragma unroll
    for (int r = 0; r < 32; r += 8)
        t[ty + r][tx] = in[(size_t)(k0 + ty + r) * N + n0 + tx];
    __syncthreads();
#pragma unroll
    for (int r = 0; r < 32; r += 8)
        out[(size_t)(n0 + ty + r) * 768 + k0 + tx] = (bf16)t[tx][ty + r];
}

// ---------------------------------------------------------------------------
// Merged GEMM for qkv (mode 0) and qk_pos (mode 1). 128x128 tile.
// A: glds double-buffered LDS (XOR swizzle). B: DIRECT L2->register fragments
// with next-iter prefetch (weights are XCD-local L2-resident after swizzle) --
// halves glds count and LDS read traffic vs staging both operands.
// XCD-aware 1D grid 960. qcat pre-scaled by c2.
// ---------------------------------------------------------------------------
__launch_bounds__(256, 3)
__global__ void k_gemm12(const bf16* __restrict__ xb, const bf16* __restrict__ posb,
                         const bf16* __restrict__ wqkvT, const bf16* __restrict__ wqkposT,
                         bf16* __restrict__ qcat, bf16* __restrict__ kcat,
                         bf16* __restrict__ vT) {
    __shared__ bf16 lA[2][128][32];   // 16 KB

    const int tid  = threadIdx.x;
    const int lane = tid & 63, wave = tid >> 6;
    const int quad = lane >> 4, col = lane & 15;
    const int sw2  = (col >> 1) & 3;
    const int wm = (wave >> 1) * 64, wn = (wave & 1) * 64;

    const int fid = blockIdx.x;
    const int xcd = fid & 7, s = fid >> 3;
    const int sx = s % 15, sy = s / 15;
    int bx = (xcd & 1) * 15 + sx;
    const int by = (xcd >> 1) * 8 + sy;

    int mode, nBase;
    const bf16 *A, *BT;
    if (bx < 18) { mode = 0; A = xb;   BT = wqkvT;   nBase = bx * 128; }
    else         { mode = 1; A = posb; BT = wqkposT; nBase = (bx - 18) * 128; }
    const int mBase = by * 128;

    const bf16* Ap = A  + (size_t)mBase * 768;
    const bf16* Bp = BT + (size_t)nBase * 768;

#define STAGE_A(buf, k0)                                                        \
    _Pragma("unroll")                                                           \
    for (int j = 0; j < 2; ++j) {                                               \
        int idx = (wave * 2 + j) * 64 + lane;                                   \
        int row = idx >> 2, c = (idx & 3) ^ ((row >> 1) & 3);                   \
        __builtin_amdgcn_global_load_lds(                                       \
            (const glob_u32*)(Ap + (size_t)row * 768 + (k0) + c * 8),           \
            (lds_u32*)((char*)&lA[buf][0][0] + (wave * 2 + j) * 1024), 16, 0, 0);\
    }

    // B row pointers for this wave's 64 n-cols (B-fragment: n=col, k contiguous)
    const bf16* Bq[4];
#pragma unroll
    for (int ni = 0; ni < 4; ++ni)
        Bq[ni] = Bp + (size_t)(wn + ni * 16 + col) * 768 + quad * 8;

    bf16x8 bcur[4], bnxt[4];
#pragma unroll
    for (int ni = 0; ni < 4; ++ni) bcur[ni] = *(const bf16x8*)(Bq[ni]);

    f32x4 acc[4][4];
#pragma unroll
    for (int mi = 0; mi < 4; ++mi)
#pragma unroll
        for (int ni = 0; ni < 4; ++ni) acc[mi][ni] = f32x4{0.f, 0.f, 0.f, 0.f};

    STAGE_A(0, 0)
#pragma unroll
    for (int it = 0; it < 24; ++it) {
        const int cur = it & 1, nxt = cur ^ 1;
        __syncthreads();
        if (it < 23) {
            STAGE_A(nxt, (it + 1) * 32)
#pragma unroll
            for (int ni = 0; ni < 4; ++ni)
                bnxt[ni] = *(const bf16x8*)(Bq[ni] + (it + 1) * 32);
        }
        bf16x8 af[4];
#pragma unroll
        for (int mi = 0; mi < 4; ++mi)
            af[mi] = *(const bf16x8*)&lA[cur][wm + mi * 16 + col][(quad ^ sw2) * 8];
#pragma unroll
        for (int mi = 0; mi < 4; ++mi)
#pragma unroll
            for (int ni = 0; ni < 4; ++ni)
                acc[mi][ni] = MFMA(af[mi], bcur[ni], acc[mi][ni]);
#pragma unroll
        for (int ni = 0; ni < 4; ++ni) bcur[ni] = bnxt[ni];
    }
#undef STAGE_A

    const float c2s = 0.018042195912f * 1.44269504089f;
    const int bb = mBase >> 10;
    const int sr0 = (mBase & 1023) + wm + quad * 4;
#pragma unroll
    for (int ni = 0; ni < 4; ++ni) {
        const int nb = nBase + wn + ni * 16;
        const int which = (mode == 0) ? (nb >= 1536 ? 2 : (nb >= 768 ? 1 : 0))
                                      : (nb >= 768 ? 1 : 0);
        const int rem = nb - which * 768;
        const int hh = rem >> 6, dd0 = rem & 63;
        const size_t hb = (size_t)(bb * 12 + hh);
        if (mode == 0 && which == 2) {
            bf16* dstv = vT + (hb * 64 + dd0 + col) * 1024 + sr0;
#pragma unroll
            for (int mi = 0; mi < 4; ++mi) {
                bf16x4v pk;
#pragma unroll
                for (int r = 0; r < 4; ++r) pk[r] = (bf16)acc[mi][ni][r];
                *(bf16x4v*)(dstv + mi * 16) = pk;
            }
        } else {
            const float scl = (which == 0) ? c2s : 1.0f;
            bf16* dstq = (which == 0 ? qcat : kcat)
                       + (hb * 1024 + sr0) * 128 + (mode == 1 ? 64 : 0) + dd0 + col;
#pragma unroll
            for (int mi = 0; mi < 4; ++mi)
#pragma unroll
                for (int r = 0; r < 4; ++r)
                    dstq[(size_t)(mi * 16 + r) * 128] = (bf16)(acc[mi][ni][r] * scl);
        }
    }
}

// ---------------------------------------------------------------------------
// Flash attention v4 (hybrid of R5 chassis + register-resident P):
// - glds double-buffered K/V tiles in LDS, shared by 4 waves, 1 barrier/iter.
// - wave owns 16 q held as Q B-fragments in registers (pre-scaled by c2).
// - S^T = K*Q^T: C-layout (kv=quad*4+r, q=col) IS the PV B-fragment layout,
//   so P goes MFMA -> exp2 -> MFMA entirely in registers (no lP round-trip).
// - PV: O^T = V^T*P^T, V read from LDS as two b64 with the kv-interleave
//   matching P's packing (kv order within a K=32 chunk is a free permutation).
// - each wave covers all kv for its q -> no cross-wave reduction, no lRed.
// LDS 48 KB -> 3 blocks/CU. 1D grid 768, XCD-pinned.
// ---------------------------------------------------------------------------
__launch_bounds__(256, 3)
__global__ void k_attn(const bf16* __restrict__ qcat, const bf16* __restrict__ kcat,
                       const bf16* __restrict__ vT, bf16* __restrict__ attn_out) {
    __shared__ bf16 lK[2][64][128];   // 32 KB (XOR-swizzled chunks)
    __shared__ bf16 lV[2][64][64];    // 16 KB (rows = v-dims, swizzled)

    const int tid  = threadIdx.x;
    const int lane = tid & 63, wave = tid >> 6;
    const int quad = lane >> 4, col = lane & 15;
    const int sw   = col & 7;
    const int q01  = quad >> 1, qlo = quad & 1;

    const int fid = blockIdx.x;
    const int xcd = fid & 7, s = fid >> 3;
    const int qt = s & 15;
    const int unit = (s >> 4) * 8 + xcd;      // == b*12+h
    const int b = unit / 12, h = unit % 12;

    const bf16* Qb = qcat + (size_t)unit * 1024 * 128;
    const bf16* Kb = kcat + (size_t)unit * 1024 * 128;
    const bf16* Vb = vT   + (size_t)unit * 64 * 1024;

    const int kidx = wave * 256 + lane;
    const int vidx = wave * 128 + lane;

#define STAGE_K(buf, kv0)                                                      \
    _Pragma("unroll")                                                          \
    for (int j = 0; j < 4; ++j) {                                              \
        int idx = kidx + j * 64;                                               \
        int row = idx >> 4, c = idx & 15, csrc = c ^ (row & 7);                \
        __builtin_amdgcn_global_load_lds(                                      \
            (const glob_u32*)(Kb + (size_t)((kv0) + row) * 128 + csrc * 8),    \
            (lds_u32*)(&lK[buf][0][0] + (wave * 4 + j) * 512), 16, 0, 0);      \
    }
#define STAGE_V(buf, kv0)                                                      \
    _Pragma("unroll")                                                          \
    for (int j = 0; j < 2; ++j) {                                              \
        int idx = vidx + j * 64;                                               \
        int row = idx >> 3, c = idx & 7, csrc = c ^ (row & 7);                 \
        __builtin_amdgcn_global_load_lds(                                      \
            (const glob_u32*)(Vb + (size_t)row * 1024 + (kv0) + csrc * 8),     \
            (lds_u32*)(&lV[buf][0][0] + (wave * 2 + j) * 512), 16, 0, 0);      \
    }

    // Q B-fragments for this wave's 16 q-rows (n=col, k=f*32+quad*8+j)
    bf16x8 qb[4];
    {
        const bf16* qrow = Qb + (size_t)(qt * 64 + wave * 16 + col) * 128;
#pragma unroll
        for (int f = 0; f < 4; ++f) qb[f] = *(const bf16x8*)(qrow + f * 32 + quad * 8);
    }

    f32x4 o[4];                        // O^T: (vd = vt*16+quad*4+r, q = col)
#pragma unroll
    for (int vt = 0; vt < 4; ++vt) o[vt] = f32x4{0.f, 0.f, 0.f, 0.f};
    float lsum = 0.f;

    STAGE_K(0, 0)
    STAGE_V(0, 0)

    for (int it = 0; it < 16; ++it) {
        const int cur = it & 1, nxt = cur ^ 1;
        __syncthreads();
        if (it < 15) {
            const int kv1 = (it + 1) * 64;
            STAGE_K(nxt, kv1)
            STAGE_V(nxt, kv1)
        }

        // S^T = K * Q^T : A-frag = K rows (m = kv_local = t*16+col)
        f32x4 st[4];
#pragma unroll
        for (int t = 0; t < 4; ++t) st[t] = f32x4{0.f, 0.f, 0.f, 0.f};
#pragma unroll
        for (int t = 0; t < 4; ++t)
#pragma unroll
            for (int f = 0; f < 4; ++f) {
                bf16x8 kf = *(const bf16x8*)&lK[cur][t * 16 + col][((f * 4 + quad) ^ sw) * 8];
                st[t] = MFMA(kf, qb[f], st[t]);
            }

        // p = exp2(s) (q pre-scaled); pack straight into PV B-fragments.
        // chunk c (kv 32) combines subtiles t=2c (j<4) and t=2c+1 (j>=4):
        // lane (quad,col) supplies kv = c*32 + [0|16] + quad*4 + j  -- exactly
        // the values this lane already holds in st[2c], st[2c+1].
        bf16x8 pbf[2];
#pragma unroll
        for (int c = 0; c < 2; ++c) {
#pragma unroll
            for (int r = 0; r < 4; ++r) {
                float p0 = exp2f(st[2 * c][r]);
                float p1 = exp2f(st[2 * c + 1][r]);
                lsum += p0 + p1;
                pbf[c][r]     = (bf16)p0;
                pbf[c][4 + r] = (bf16)p1;
            }
        }

        // O^T += V^T * P^T. V A-frag (m=vd=vt*16+col, k matching interleave):
        // part0 at logical kv chunk c*4+q01 (8B half qlo), part1 at c*4+2+q01.
#pragma unroll
        for (int c = 0; c < 2; ++c)
#pragma unroll
            for (int vt = 0; vt < 4; ++vt) {
                const bf16* vrow = &lV[cur][vt * 16 + col][0];
                bf16x4v va = *(const bf16x4v*)(vrow + ((c * 4 + q01) ^ sw) * 8 + qlo * 4);
                bf16x4v vb = *(const bf16x4v*)(vrow + ((c * 4 + 2 + q01) ^ sw) * 8 + qlo * 4);
                bf16x8 vf;
#pragma unroll
                for (int i = 0; i < 4; ++i) { vf[i] = va[i]; vf[4 + i] = vb[i]; }
                o[vt] = MFMA(vf, pbf[c], o[vt]);
            }
    }

    // denominator: sum over the 4 quads holding q=col's kv partitions
    float l = lsum;
    l += __shfl_xor(l, 16, 64);
    l += __shfl_xor(l, 32, 64);
    const float inv = 1.f / l;

    // store: q = qt*64+wave*16+col (row), vd = vt*16+quad*4+r (col)
    const int qrow = qt * 64 + wave * 16 + col;
    bf16* dst = attn_out + ((size_t)b * 1024 + qrow) * 768 + h * 64;
#pragma unroll
    for (int vt = 0; vt < 4; ++vt)
#pragma unroll
        for (int r = 0; r < 4; ++r)
            dst[vt * 16 + quad * 4 + r] = (bf16)(o[vt][r] * inv);
#undef STAGE_K
#undef STAGE_V
}

// ---------------------------------------------------------------------------
// Out projection: out[4096][768] = aout @ woutT^T + bias (fp32 out)
// 128m x 64n tiles, glds double-buffered. 1D grid 384, XCD-aware 6bx x 8by.
// ---------------------------------------------------------------------------
__launch_bounds__(256, 3)
__global__ void k_gemm_out(const bf16* __restrict__ aout, const bf16* __restrict__ woutT,
                           const float* __restrict__ bias, float* __restrict__ out) {
    __shared__ bf16 lA[2][128][32];
    __shared__ bf16 lB[2][64][32];

    const int tid  = threadIdx.x;
    const int lane = tid & 63, wave = tid >> 6;
    const int quad = lane >> 4, col = lane & 15;
    const int sw2  = (col >> 1) & 3;
    const int wm = (wave >> 1) * 64, wn = (wave & 1) * 32;

    const int fid = blockIdx.x;
    const int xcd = fid & 7, s = fid >> 3;
    const int sx = s % 6, sy = s / 6;
    const int bx = (xcd & 1) * 6 + sx;
    const int by = (xcd >> 1) * 8 + sy;

    const int mBase = by * 128, nBase = bx * 64;

    const bf16* Ap = aout  + (size_t)mBase * 768;
    const bf16* Bp = woutT + (size_t)nBase * 768;

#define STAGE_O(buf, k0)                                                        \
    _Pragma("unroll")                                                           \
    for (int j = 0; j < 2; ++j) {                                               \
        int idx = (wave * 2 + j) * 64 + lane;                                   \
        int row = idx >> 2, c = (idx & 3) ^ ((row >> 1) & 3);                   \
        __builtin_amdgcn_global_load_lds(                                       \
            (const glob_u32*)(Ap + (size_t)row * 768 + (k0) + c * 8),           \
            (lds_u32*)((char*)&lA[buf][0][0] + (wave * 2 + j) * 1024), 16, 0, 0);\
    }                                                                           \
    {                                                                           \
        int idx = wave * 64 + lane;                                             \
        int row = idx >> 2, c = (idx & 3) ^ ((row >> 1) & 3);                   \
        __builtin_amdgcn_global_load_lds(                                       \
            (const glob_u32*)(Bp + (size_t)row * 768 + (k0) + c * 8),           \
            (lds_u32*)((char*)&lB[buf][0][0] + wave * 1024), 16, 0, 0);         \
    }

    f32x4 acc[4][2];
#pragma unroll
    for (int mi = 0; mi < 4; ++mi)
#pragma unroll
        for (int ni = 0; ni < 2; ++ni) acc[mi][ni] = f32x4{0.f, 0.f, 0.f, 0.f};

    STAGE_O(0, 0)
    for (int it = 0; it < 24; ++it) {
        const int cur = it & 1, nxt = cur ^ 1;
        __syncthreads();
        if (it < 23) STAGE_O(nxt, (it + 1) * 32)

        bf16x8 af[4], bfg[2];
#pragma unroll
        for (int mi = 0; mi < 4; ++mi)
            af[mi]  = *(const bf16x8*)&lA[cur][wm + mi * 16 + col][(quad ^ sw2) * 8];
#pragma unroll
        for (int ni = 0; ni < 2; ++ni)
            bfg[ni] = *(const bf16x8*)&lB[cur][wn + ni * 16 + col][(quad ^ sw2) * 8];
#pragma unroll
        for (int mi = 0; mi < 4; ++mi)
#pragma unroll
            for (int ni = 0; ni < 2; ++ni)
                acc[mi][ni] = MFMA(af[mi], bfg[ni], acc[mi][ni]);
    }
#undef STAGE_O

#pragma unroll
    for (int mi = 0; mi < 4; ++mi)
#pragma unroll
        for (int ni = 0; ni < 2; ++ni)
#pragma unroll
            for (int r = 0; r < 4; ++r) {
                int m = mBase + wm + mi * 16 + quad * 4 + r;
                int n = nBase + wn + ni * 16 + col;
                out[(size_t)m * 768 + n] = acc[mi][ni][r] + bias[n];
            }
}

// ---------------------------------------------------------------------------
// Workspace layout (bytes): total 57409536 B
// ---------------------------------------------------------------------------
extern "C" void kernel_launch(void* const* d_in, const int* in_sizes, int n_in,
                              void* d_out, int out_size, void* d_ws, size_t ws_size,
                              hipStream_t stream) {
    const float* x        = (const float*)d_in[0];
    const float* pos      = (const float*)d_in[1];
    const float* w_qkv    = (const float*)d_in[2];
    const float* w_qk_pos = (const float*)d_in[3];
    const float* w_out    = (const float*)d_in[4];
    const float* b_out    = (const float*)d_in[5];
    float* out = (float*)d_out;

    char* ws = (char*)d_ws;
    bf16* xb      = (bf16*)(ws);
    bf16* posb    = (bf16*)(ws + 6291456);
    bf16* wqkvT   = (bf16*)(ws + 12582912);
    bf16* wqkposT = (bf16*)(ws + 16121856);
    bf16* woutT   = (bf16*)(ws + 18481152);
    bf16* qcat    = (bf16*)(ws + 19660800);
    bf16* kcat    = (bf16*)(ws + 32243712);
    bf16* vT      = (bf16*)(ws + 44826624);
    bf16* aout    = (bf16*)(ws + 51118080);

    k_cvt2<<<6144, 256, 0, stream>>>(x, pos, xb, posb);
    k_tr<<<dim3(144, 24), 256, 0, stream>>>(w_qkv, w_qk_pos, w_out, wqkvT, wqkposT, woutT);
    k_gemm12<<<960, 256, 0, stream>>>(xb, posb, wqkvT, wqkposT, qcat, kcat, vT);
    k_attn<<<768, 256, 0, stream>>>(qcat, kcat, vT, aout);
    k_gemm_out<<<384, 256, 0, stream>>>(aout, woutT, b_out, out);
}

// Round 8
// 178.558 us; speedup vs baseline: 1.1283x; 1.1283x over previous
//
#include <hip/hip_runtime.h>
#include <cstdint>
#include <cstddef>

typedef __bf16 bf16;
typedef __bf16 bf16x8 __attribute__((ext_vector_type(8)));
typedef __bf16 bf16x4v __attribute__((ext_vector_type(4)));
typedef float  f32x4  __attribute__((ext_vector_type(4)));

#define MFMA(a, b, c) __builtin_amdgcn_mfma_f32_16x16x32_bf16((a), (b), (c), 0, 0, 0)

typedef __attribute__((address_space(3))) unsigned int  lds_u32;
typedef __attribute__((address_space(1))) unsigned int glob_u32;

// B=4, N=1024, DIM=768, HEADS=12, DIM_HEAD=64, INNER=768
// c2 = 0.5/sqrt(768)*log2(e) is folded into qcat by k_gemm12's epilogue.

// ---------------------------------------------------------------------------
// Merged prep: blocks [0,6144) = fp32->bf16 convert of x|pos;
// blocks [6144,9600) = transposing convert of the 3 weights.
// One launch instead of two (saves a serial kernel tail).
// ---------------------------------------------------------------------------
__global__ void k_prep(const float* __restrict__ x, const float* __restrict__ pos,
                       const float* __restrict__ w_qkv, const float* __restrict__ w_qk_pos,
                       const float* __restrict__ w_out,
                       bf16* __restrict__ xb, bf16* __restrict__ posb,
                       bf16* __restrict__ wqkvT, bf16* __restrict__ wqkposT,
                       bf16* __restrict__ woutT) {
    __shared__ float t[32][33];
    const int blk = blockIdx.x;
    if (blk < 6144) {
        int i = blk * 256 + threadIdx.x;
        const float* in = x; bf16* out = xb;
        if (i >= 786432) { i -= 786432; in = pos; out = posb; }
        float4 v = reinterpret_cast<const float4*>(in)[i];
        bf16x4v o; o[0] = (bf16)v.x; o[1] = (bf16)v.y; o[2] = (bf16)v.z; o[3] = (bf16)v.w;
        reinterpret_cast<bf16x4v*>(out)[i] = o;
        return;
    }
    int bx = (blk - 6144) % 144, ky = (blk - 6144) / 144;
    const float* in; bf16* out; int N;
    if (bx < 72)       { in = w_qkv;    out = wqkvT;   N = 2304; }
    else if (bx < 120) { in = w_qk_pos; out = wqkposT; N = 1536; bx -= 72; }
    else               { in = w_out;    out = woutT;   N = 768;  bx -= 120; }
    const int n0 = bx * 32, k0 = ky * 32;
    const int tx = threadIdx.x & 31, ty = threadIdx.x >> 5;
#pragma unroll
    for (int r = 0; r < 32; r += 8)
        t[ty + r][tx] = in[(size_t)(k0 + ty + r) * N + n0 + tx];
    __syncthreads();
#pragma unroll
    for (int r = 0; r < 32; r += 8)
        out[(size_t)(n0 + ty + r) * 768 + k0 + tx] = (bf16)t[tx][ty + r];
}

// ---------------------------------------------------------------------------
// Merged GEMM for qkv (mode 0) and qk_pos (mode 1). 128x128 tile, BOTH
// operands glds double-buffered into XOR-swizzled LDS (proven R5 structure;
// R7's B-from-L2 regressed: per-lane strided gather = ~16 txn/load at L2
// latency with 1-iter prefetch depth, vs glds whose barrier drain overlaps a
// full iteration). XCD-aware 1D grid 960. qcat pre-scaled by c2.
// ---------------------------------------------------------------------------
__launch_bounds__(256, 3)
__global__ void k_gemm12(const bf16* __restrict__ xb, const bf16* __restrict__ posb,
                         const bf16* __restrict__ wqkvT, const bf16* __restrict__ wqkposT,
                         bf16* __restrict__ qcat, bf16* __restrict__ kcat,
                         bf16* __restrict__ vT) {
    __shared__ bf16 lA[2][128][32];
    __shared__ bf16 lB[2][128][32];

    const int tid  = threadIdx.x;
    const int lane = tid & 63, wave = tid >> 6;
    const int quad = lane >> 4, col = lane & 15;
    const int sw2  = (col >> 1) & 3;
    const int wm = (wave >> 1) * 64, wn = (wave & 1) * 64;

    const int fid = blockIdx.x;
    const int xcd = fid & 7, s = fid >> 3;
    const int sx = s % 15, sy = s / 15;
    int bx = (xcd & 1) * 15 + sx;
    const int by = (xcd >> 1) * 8 + sy;

    int mode, nBase;
    const bf16 *A, *BT;
    if (bx < 18) { mode = 0; A = xb;   BT = wqkvT;   nBase = bx * 128; }
    else         { mode = 1; A = posb; BT = wqkposT; nBase = (bx - 18) * 128; }
    const int mBase = by * 128;

    const bf16* Ap = A  + (size_t)mBase * 768;
    const bf16* Bp = BT + (size_t)nBase * 768;

#define STAGE12(buf, k0)                                                        \
    _Pragma("unroll")                                                           \
    for (int j = 0; j < 2; ++j) {                                               \
        int idx = (wave * 2 + j) * 64 + lane;                                   \
        int row = idx >> 2, c = (idx & 3) ^ ((row >> 1) & 3);                   \
        __builtin_amdgcn_global_load_lds(                                       \
            (const glob_u32*)(Ap + (size_t)row * 768 + (k0) + c * 8),           \
            (lds_u32*)((char*)&lA[buf][0][0] + (wave * 2 + j) * 1024), 16, 0, 0);\
        __builtin_amdgcn_global_load_lds(                                       \
            (const glob_u32*)(Bp + (size_t)row * 768 + (k0) + c * 8),           \
            (lds_u32*)((char*)&lB[buf][0][0] + (wave * 2 + j) * 1024), 16, 0, 0);\
    }

    f32x4 acc[4][4];
#pragma unroll
    for (int mi = 0; mi < 4; ++mi)
#pragma unroll
        for (int ni = 0; ni < 4; ++ni) acc[mi][ni] = f32x4{0.f, 0.f, 0.f, 0.f};

    STAGE12(0, 0)
    for (int it = 0; it < 24; ++it) {
        const int cur = it & 1, nxt = cur ^ 1;
        __syncthreads();
        if (it < 23) STAGE12(nxt, (it + 1) * 32)

        bf16x8 af[4], bfg[4];
#pragma unroll
        for (int mi = 0; mi < 4; ++mi)
            af[mi]  = *(const bf16x8*)&lA[cur][wm + mi * 16 + col][(quad ^ sw2) * 8];
#pragma unroll
        for (int ni = 0; ni < 4; ++ni)
            bfg[ni] = *(const bf16x8*)&lB[cur][wn + ni * 16 + col][(quad ^ sw2) * 8];
#pragma unroll
        for (int mi = 0; mi < 4; ++mi)
#pragma unroll
            for (int ni = 0; ni < 4; ++ni)
                acc[mi][ni] = MFMA(af[mi], bfg[ni], acc[mi][ni]);
    }
#undef STAGE12

    const float c2s = 0.018042195912f * 1.44269504089f;
    const int bb = mBase >> 10;
    const int sr0 = (mBase & 1023) + wm + quad * 4;
#pragma unroll
    for (int ni = 0; ni < 4; ++ni) {
        const int nb = nBase + wn + ni * 16;
        const int which = (mode == 0) ? (nb >= 1536 ? 2 : (nb >= 768 ? 1 : 0))
                                      : (nb >= 768 ? 1 : 0);
        const int rem = nb - which * 768;
        const int hh = rem >> 6, dd0 = rem & 63;
        const size_t hb = (size_t)(bb * 12 + hh);
        if (mode == 0 && which == 2) {
            bf16* dstv = vT + (hb * 64 + dd0 + col) * 1024 + sr0;
#pragma unroll
            for (int mi = 0; mi < 4; ++mi) {
                bf16x4v pk;
#pragma unroll
                for (int r = 0; r < 4; ++r) pk[r] = (bf16)acc[mi][ni][r];
                *(bf16x4v*)(dstv + mi * 16) = pk;
            }
        } else {
            const float scl = (which == 0) ? c2s : 1.0f;
            bf16* dstq = (which == 0 ? qcat : kcat)
                       + (hb * 1024 + sr0) * 128 + (mode == 1 ? 64 : 0) + dd0 + col;
#pragma unroll
            for (int mi = 0; mi < 4; ++mi)
#pragma unroll
                for (int r = 0; r < 4; ++r)
                    dstq[(size_t)(mi * 16 + r) * 128] = (bf16)(acc[mi][ni][r] * scl);
        }
    }
}

// ---------------------------------------------------------------------------
// Flash attention v4 (unchanged from R7 — improved there):
// glds double-buffered K/V, wave-owned Q B-fragments, S^T = K*Q^T so P stays
// in registers (C-layout == PV B-fragment layout), O^T = V^T*P^T,
// no cross-wave reduction. LDS 48 KB -> 3 blocks/CU. Grid 768 XCD-pinned.
// ---------------------------------------------------------------------------
__launch_bounds__(256, 3)
__global__ void k_attn(const bf16* __restrict__ qcat, const bf16* __restrict__ kcat,
                       const bf16* __restrict__ vT, bf16* __restrict__ attn_out) {
    __shared__ bf16 lK[2][64][128];
    __shared__ bf16 lV[2][64][64];

    const int tid  = threadIdx.x;
    const int lane = tid & 63, wave = tid >> 6;
    const int quad = lane >> 4, col = lane & 15;
    const int sw   = col & 7;
    const int q01  = quad >> 1, qlo = quad & 1;

    const int fid = blockIdx.x;
    const int xcd = fid & 7, s = fid >> 3;
    const int qt = s & 15;
    const int unit = (s >> 4) * 8 + xcd;
    const int b = unit / 12, h = unit % 12;

    const bf16* Qb = qcat + (size_t)unit * 1024 * 128;
    const bf16* Kb = kcat + (size_t)unit * 1024 * 128;
    const bf16* Vb = vT   + (size_t)unit * 64 * 1024;

    const int kidx = wave * 256 + lane;
    const int vidx = wave * 128 + lane;

#define STAGE_K(buf, kv0)                                                      \
    _Pragma("unroll")                                                          \
    for (int j = 0; j < 4; ++j) {                                              \
        int idx = kidx + j * 64;                                               \
        int row = idx >> 4, c = idx & 15, csrc = c ^ (row & 7);                \
        __builtin_amdgcn_global_load_lds(                                      \
            (const glob_u32*)(Kb + (size_t)((kv0) + row) * 128 + csrc * 8),    \
            (lds_u32*)(&lK[buf][0][0] + (wave * 4 + j) * 512), 16, 0, 0);      \
    }
#define STAGE_V(buf, kv0)                                                      \
    _Pragma("unroll")                                                          \
    for (int j = 0; j < 2; ++j) {                                              \
        int idx = vidx + j * 64;                                               \
        int row = idx >> 3, c = idx & 7, csrc = c ^ (row & 7);                 \
        __builtin_amdgcn_global_load_lds(                                      \
            (const glob_u32*)(Vb + (size_t)row * 1024 + (kv0) + csrc * 8),     \
            (lds_u32*)(&lV[buf][0][0] + (wave * 2 + j) * 512), 16, 0, 0);      \
    }

    bf16x8 qb[4];
    {
        const bf16* qrow = Qb + (size_t)(qt * 64 + wave * 16 + col) * 128;
#pragma unroll
        for (int f = 0; f < 4; ++f) qb[f] = *(const bf16x8*)(qrow + f * 32 + quad * 8);
    }

    f32x4 o[4];
#pragma unroll
    for (int vt = 0; vt < 4; ++vt) o[vt] = f32x4{0.f, 0.f, 0.f, 0.f};
    float lsum = 0.f;

    STAGE_K(0, 0)
    STAGE_V(0, 0)

    for (int it = 0; it < 16; ++it) {
        const int cur = it & 1, nxt = cur ^ 1;
        __syncthreads();
        if (it < 15) {
            const int kv1 = (it + 1) * 64;
            STAGE_K(nxt, kv1)
            STAGE_V(nxt, kv1)
        }

        f32x4 st[4];
#pragma unroll
        for (int t = 0; t < 4; ++t) st[t] = f32x4{0.f, 0.f, 0.f, 0.f};
#pragma unroll
        for (int t = 0; t < 4; ++t)
#pragma unroll
            for (int f = 0; f < 4; ++f) {
                bf16x8 kf = *(const bf16x8*)&lK[cur][t * 16 + col][((f * 4 + quad) ^ sw) * 8];
                st[t] = MFMA(kf, qb[f], st[t]);
            }

        bf16x8 pbf[2];
#pragma unroll
        for (int c = 0; c < 2; ++c) {
#pragma unroll
            for (int r = 0; r < 4; ++r) {
                float p0 = exp2f(st[2 * c][r]);
                float p1 = exp2f(st[2 * c + 1][r]);
                lsum += p0 + p1;
                pbf[c][r]     = (bf16)p0;
                pbf[c][4 + r] = (bf16)p1;
            }
        }

#pragma unroll
        for (int c = 0; c < 2; ++c)
#pragma unroll
            for (int vt = 0; vt < 4; ++vt) {
                const bf16* vrow = &lV[cur][vt * 16 + col][0];
                bf16x4v va = *(const bf16x4v*)(vrow + ((c * 4 + q01) ^ sw) * 8 + qlo * 4);
                bf16x4v vb = *(const bf16x4v*)(vrow + ((c * 4 + 2 + q01) ^ sw) * 8 + qlo * 4);
                bf16x8 vf;
#pragma unroll
                for (int i = 0; i < 4; ++i) { vf[i] = va[i]; vf[4 + i] = vb[i]; }
                o[vt] = MFMA(vf, pbf[c], o[vt]);
            }
    }

    float l = lsum;
    l += __shfl_xor(l, 16, 64);
    l += __shfl_xor(l, 32, 64);
    const float inv = 1.f / l;

    const int qrow = qt * 64 + wave * 16 + col;
    bf16* dst = attn_out + ((size_t)b * 1024 + qrow) * 768 + h * 64;
#pragma unroll
    for (int vt = 0; vt < 4; ++vt)
#pragma unroll
        for (int r = 0; r < 4; ++r)
            dst[vt * 16 + quad * 4 + r] = (bf16)(o[vt][r] * inv);
#undef STAGE_K
#undef STAGE_V
}

// ---------------------------------------------------------------------------
// Out projection: out[4096][768] = aout @ woutT^T + bias (fp32 out)
// 128m x 64n tiles, glds double-buffered. 1D grid 384, XCD-aware 6bx x 8by.
// ---------------------------------------------------------------------------
__launch_bounds__(256, 3)
__global__ void k_gemm_out(const bf16* __restrict__ aout, const bf16* __restrict__ woutT,
                           const float* __restrict__ bias, float* __restrict__ out) {
    __shared__ bf16 lA[2][128][32];
    __shared__ bf16 lB[2][64][32];

    const int tid  = threadIdx.x;
    const int lane = tid & 63, wave = tid >> 6;
    const int quad = lane >> 4, col = lane & 15;
    const int sw2  = (col >> 1) & 3;
    const int wm = (wave >> 1) * 64, wn = (wave & 1) * 32;

    const int fid = blockIdx.x;
    const int xcd = fid & 7, s = fid >> 3;
    const int sx = s % 6, sy = s / 6;
    const int bx = (xcd & 1) * 6 + sx;
    const int by = (xcd >> 1) * 8 + sy;

    const int mBase = by * 128, nBase = bx * 64;

    const bf16* Ap = aout  + (size_t)mBase * 768;
    const bf16* Bp = woutT + (size_t)nBase * 768;

#define STAGE_O(buf, k0)                                                        \
    _Pragma("unroll")                                                           \
    for (int j = 0; j < 2; ++j) {                                               \
        int idx = (wave * 2 + j) * 64 + lane;                                   \
        int row = idx >> 2, c = (idx & 3) ^ ((row >> 1) & 3);                   \
        __builtin_amdgcn_global_load_lds(                                       \
            (const glob_u32*)(Ap + (size_t)row * 768 + (k0) + c * 8),           \
            (lds_u32*)((char*)&lA[buf][0][0] + (wave * 2 + j) * 1024), 16, 0, 0);\
    }                                                                           \
    {                                                                           \
        int idx = wave * 64 + lane;                                             \
        int row = idx >> 2, c = (idx & 3) ^ ((row >> 1) & 3);                   \
        __builtin_amdgcn_global_load_lds(                                       \
            (const glob_u32*)(Bp + (size_t)row * 768 + (k0) + c * 8),           \
            (lds_u32*)((char*)&lB[buf][0][0] + wave * 1024), 16, 0, 0);         \
    }

    f32x4 acc[4][2];
#pragma unroll
    for (int mi = 0; mi < 4; ++mi)
#pragma unroll
        for (int ni = 0; ni < 2; ++ni) acc[mi][ni] = f32x4{0.f, 0.f, 0.f, 0.f};

    STAGE_O(0, 0)
    for (int it = 0; it < 24; ++it) {
        const int cur = it & 1, nxt = cur ^ 1;
        __syncthreads();
        if (it < 23) STAGE_O(nxt, (it + 1) * 32)

        bf16x8 af[4], bfg[2];
#pragma unroll
        for (int mi = 0; mi < 4; ++mi)
            af[mi]  = *(const bf16x8*)&lA[cur][wm + mi * 16 + col][(quad ^ sw2) * 8];
#pragma unroll
        for (int ni = 0; ni < 2; ++ni)
            bfg[ni] = *(const bf16x8*)&lB[cur][wn + ni * 16 + col][(quad ^ sw2) * 8];
#pragma unroll
        for (int mi = 0; mi < 4; ++mi)
#pragma unroll
            for (int ni = 0; ni < 2; ++ni)
                acc[mi][ni] = MFMA(af[mi], bfg[ni], acc[mi][ni]);
    }
#undef STAGE_O

#pragma unroll
    for (int mi = 0; mi < 4; ++mi)
#pragma unroll
        for (int ni = 0; ni < 2; ++ni)
#pragma unroll
            for (int r = 0; r < 4; ++r) {
                int m = mBase + wm + mi * 16 + quad * 4 + r;
                int n = nBase + wn + ni * 16 + col;
                out[(size_t)m * 768 + n] = acc[mi][ni][r] + bias[n];
            }
}

// ---------------------------------------------------------------------------
// Workspace layout (bytes): total 57409536 B
// ---------------------------------------------------------------------------
extern "C" void kernel_launch(void* const* d_in, const int* in_sizes, int n_in,
                              void* d_out, int out_size, void* d_ws, size_t ws_size,
                              hipStream_t stream) {
    const float* x        = (const float*)d_in[0];
    const float* pos      = (const float*)d_in[1];
    const float* w_qkv    = (const float*)d_in[2];
    const float* w_qk_pos = (const float*)d_in[3];
    const float* w_out    = (const float*)d_in[4];
    const float* b_out    = (const float*)d_in[5];
    float* out = (float*)d_out;

    char* ws = (char*)d_ws;
    bf16* xb      = (bf16*)(ws);
    bf16* posb    = (bf16*)(ws + 6291456);
    bf16* wqkvT   = (bf16*)(ws + 12582912);
    bf16* wqkposT = (bf16*)(ws + 16121856);
    bf16* woutT   = (bf16*)(ws + 18481152);
    bf16* qcat    = (bf16*)(ws + 19660800);
    bf16* kcat    = (bf16*)(ws + 32243712);
    bf16* vT      = (bf16*)(ws + 44826624);
    bf16* aout    = (bf16*)(ws + 51118080);

    k_prep<<<9600, 256, 0, stream>>>(x, pos, w_qkv, w_qk_pos, w_out,
                                     xb, posb, wqkvT, wqkposT, woutT);
    k_gemm12<<<960, 256, 0, stream>>>(xb, posb, wqkvT, wqkposT, qcat, kcat, vT);
    k_attn<<<768, 256, 0, stream>>>(qcat, kcat, vT, aout);
    k_gemm_out<<<384, 256, 0, stream>>>(aout, woutT, b_out, out);
}

// Round 9
// 173.924 us; speedup vs baseline: 1.1583x; 1.0266x over previous
//
#include <hip/hip_runtime.h>
#include <cstdint>
#include <cstddef>

typedef __bf16 bf16;
typedef __bf16 bf16x8 __attribute__((ext_vector_type(8)));
typedef __bf16 bf16x4v __attribute__((ext_vector_type(4)));
typedef float  f32x4  __attribute__((ext_vector_type(4)));

#define MFMA(a, b, c) __builtin_amdgcn_mfma_f32_16x16x32_bf16((a), (b), (c), 0, 0, 0)

typedef __attribute__((address_space(3))) unsigned int  lds_u32;
typedef __attribute__((address_space(1))) unsigned int glob_u32;

// B=4, N=1024, DIM=768, HEADS=12, DIM_HEAD=64, INNER=768
// c2 = 0.5/sqrt(768)*log2(e) is folded into qcat by k_gemm12's epilogue.

// ---------------------------------------------------------------------------
// Merged prep: blocks [0,6144) = fp32->bf16 convert of x|pos;
// blocks [6144,9600) = transposing convert of the 3 weights.
// ---------------------------------------------------------------------------
__global__ void k_prep(const float* __restrict__ x, const float* __restrict__ pos,
                       const float* __restrict__ w_qkv, const float* __restrict__ w_qk_pos,
                       const float* __restrict__ w_out,
                       bf16* __restrict__ xb, bf16* __restrict__ posb,
                       bf16* __restrict__ wqkvT, bf16* __restrict__ wqkposT,
                       bf16* __restrict__ woutT) {
    __shared__ float t[32][33];
    const int blk = blockIdx.x;
    if (blk < 6144) {
        int i = blk * 256 + threadIdx.x;
        const float* in = x; bf16* out = xb;
        if (i >= 786432) { i -= 786432; in = pos; out = posb; }
        float4 v = reinterpret_cast<const float4*>(in)[i];
        bf16x4v o; o[0] = (bf16)v.x; o[1] = (bf16)v.y; o[2] = (bf16)v.z; o[3] = (bf16)v.w;
        reinterpret_cast<bf16x4v*>(out)[i] = o;
        return;
    }
    int bx = (blk - 6144) % 144, ky = (blk - 6144) / 144;
    const float* in; bf16* out; int N;
    if (bx < 72)       { in = w_qkv;    out = wqkvT;   N = 2304; }
    else if (bx < 120) { in = w_qk_pos; out = wqkposT; N = 1536; bx -= 72; }
    else               { in = w_out;    out = woutT;   N = 768;  bx -= 120; }
    const int n0 = bx * 32, k0 = ky * 32;
    const int tx = threadIdx.x & 31, ty = threadIdx.x >> 5;
#pragma unroll
    for (int r = 0; r < 32; r += 8)
        t[ty + r][tx] = in[(size_t)(k0 + ty + r) * N + n0 + tx];
    __syncthreads();
#pragma unroll
    for (int r = 0; r < 32; r += 8)
        out[(size_t)(n0 + ty + r) * 768 + k0 + tx] = (bf16)t[tx][ty + r];
}

// ---------------------------------------------------------------------------
// Merged GEMM for qkv (mode 0) and qk_pos (mode 1). 128x128 tile, both
// operands glds double-buffered into XOR-swizzled LDS (proven structure).
// XCD-aware 1D grid 960. qcat pre-scaled by c2.
// ---------------------------------------------------------------------------
__launch_bounds__(256, 3)
__global__ void k_gemm12(const bf16* __restrict__ xb, const bf16* __restrict__ posb,
                         const bf16* __restrict__ wqkvT, const bf16* __restrict__ wqkposT,
                         bf16* __restrict__ qcat, bf16* __restrict__ kcat,
                         bf16* __restrict__ vT) {
    __shared__ bf16 lA[2][128][32];
    __shared__ bf16 lB[2][128][32];

    const int tid  = threadIdx.x;
    const int lane = tid & 63, wave = tid >> 6;
    const int quad = lane >> 4, col = lane & 15;
    const int sw2  = (col >> 1) & 3;
    const int wm = (wave >> 1) * 64, wn = (wave & 1) * 64;

    const int fid = blockIdx.x;
    const int xcd = fid & 7, s = fid >> 3;
    const int sx = s % 15, sy = s / 15;
    int bx = (xcd & 1) * 15 + sx;
    const int by = (xcd >> 1) * 8 + sy;

    int mode, nBase;
    const bf16 *A, *BT;
    if (bx < 18) { mode = 0; A = xb;   BT = wqkvT;   nBase = bx * 128; }
    else         { mode = 1; A = posb; BT = wqkposT; nBase = (bx - 18) * 128; }
    const int mBase = by * 128;

    const bf16* Ap = A  + (size_t)mBase * 768;
    const bf16* Bp = BT + (size_t)nBase * 768;

#define STAGE12(buf, k0)                                                        \
    _Pragma("unroll")                                                           \
    for (int j = 0; j < 2; ++j) {                                               \
        int idx = (wave * 2 + j) * 64 + lane;                                   \
        int row = idx >> 2, c = (idx & 3) ^ ((row >> 1) & 3);                   \
        __builtin_amdgcn_global_load_lds(                                       \
            (const glob_u32*)(Ap + (size_t)row * 768 + (k0) + c * 8),           \
            (lds_u32*)((char*)&lA[buf][0][0] + (wave * 2 + j) * 1024), 16, 0, 0);\
        __builtin_amdgcn_global_load_lds(                                       \
            (const glob_u32*)(Bp + (size_t)row * 768 + (k0) + c * 8),           \
            (lds_u32*)((char*)&lB[buf][0][0] + (wave * 2 + j) * 1024), 16, 0, 0);\
    }

    f32x4 acc[4][4];
#pragma unroll
    for (int mi = 0; mi < 4; ++mi)
#pragma unroll
        for (int ni = 0; ni < 4; ++ni) acc[mi][ni] = f32x4{0.f, 0.f, 0.f, 0.f};

    STAGE12(0, 0)
    for (int it = 0; it < 24; ++it) {
        const int cur = it & 1, nxt = cur ^ 1;
        __syncthreads();
        if (it < 23) STAGE12(nxt, (it + 1) * 32)

        bf16x8 af[4], bfg[4];
#pragma unroll
        for (int mi = 0; mi < 4; ++mi)
            af[mi]  = *(const bf16x8*)&lA[cur][wm + mi * 16 + col][(quad ^ sw2) * 8];
#pragma unroll
        for (int ni = 0; ni < 4; ++ni)
            bfg[ni] = *(const bf16x8*)&lB[cur][wn + ni * 16 + col][(quad ^ sw2) * 8];
#pragma unroll
        for (int mi = 0; mi < 4; ++mi)
#pragma unroll
            for (int ni = 0; ni < 4; ++ni)
                acc[mi][ni] = MFMA(af[mi], bfg[ni], acc[mi][ni]);
    }
#undef STAGE12

    const float c2s = 0.018042195912f * 1.44269504089f;
    const int bb = mBase >> 10;
    const int sr0 = (mBase & 1023) + wm + quad * 4;
#pragma unroll
    for (int ni = 0; ni < 4; ++ni) {
        const int nb = nBase + wn + ni * 16;
        const int which = (mode == 0) ? (nb >= 1536 ? 2 : (nb >= 768 ? 1 : 0))
                                      : (nb >= 768 ? 1 : 0);
        const int rem = nb - which * 768;
        const int hh = rem >> 6, dd0 = rem & 63;
        const size_t hb = (size_t)(bb * 12 + hh);
        if (mode == 0 && which == 2) {
            bf16* dstv = vT + (hb * 64 + dd0 + col) * 1024 + sr0;
#pragma unroll
            for (int mi = 0; mi < 4; ++mi) {
                bf16x4v pk;
#pragma unroll
                for (int r = 0; r < 4; ++r) pk[r] = (bf16)acc[mi][ni][r];
                *(bf16x4v*)(dstv + mi * 16) = pk;
            }
        } else {
            const float scl = (which == 0) ? c2s : 1.0f;
            bf16* dstq = (which == 0 ? qcat : kcat)
                       + (hb * 1024 + sr0) * 128 + (mode == 1 ? 64 : 0) + dd0 + col;
#pragma unroll
            for (int mi = 0; mi < 4; ++mi)
#pragma unroll
                for (int r = 0; r < 4; ++r)
                    dstq[(size_t)(mi * 16 + r) * 128] = (bf16)(acc[mi][ni][r] * scl);
        }
    }
}

// ---------------------------------------------------------------------------
// Flash attention v5: register-resident P (R7/R8) + conflict-free V.
// V staged explicitly (global b128 -> VGPR -> 2x ds_write_b64) into a PADDED
// [64][72] tile with kv sigma-permutation pre-applied:
//   kv = c*32 + h*16 + qhat*4 + i  ->  kv' = c*32 + qhat*8 + h*4 + i
// so each PV V-fragment is ONE b128 read; padded rows (144 B = 36 dwords,
// 36%32=4) give 8 lanes x 16 B per 4-bank group = conflict-free minimum.
// V loads issued right after the barrier; ds_writes deferred to end of the
// compute phase so their vmcnt wait is fully covered.
// K staging via glds unchanged. LDS 50.6 KB -> 3 blocks/CU. Grid 768 XCD-pinned.
// ---------------------------------------------------------------------------
__launch_bounds__(256, 3)
__global__ void k_attn(const bf16* __restrict__ qcat, const bf16* __restrict__ kcat,
                       const bf16* __restrict__ vT, bf16* __restrict__ attn_out) {
    __shared__ bf16 lK[2][64][128];   // 32 KB, XOR-swizzled chunks (glds)
    __shared__ bf16 lV[2][64][72];    // 18.4 KB, padded + sigma-permuted

    const int tid  = threadIdx.x;
    const int lane = tid & 63, wave = tid >> 6;
    const int quad = lane >> 4, col = lane & 15;
    const int sw   = col & 7;

    const int fid = blockIdx.x;
    const int xcd = fid & 7, s = fid >> 3;
    const int qt = s & 15;
    const int unit = (s >> 4) * 8 + xcd;
    const int b = unit / 12, h = unit % 12;

    const bf16* Qb = qcat + (size_t)unit * 1024 * 128;
    const bf16* Kb = kcat + (size_t)unit * 1024 * 128;
    const bf16* Vb = vT   + (size_t)unit * 64 * 1024;

    const int kidx = wave * 256 + lane;

#define STAGE_K(buf, kv0)                                                      \
    _Pragma("unroll")                                                          \
    for (int j = 0; j < 4; ++j) {                                              \
        int idx = kidx + j * 64;                                               \
        int row = idx >> 4, c = idx & 15, csrc = c ^ (row & 7);                \
        __builtin_amdgcn_global_load_lds(                                      \
            (const glob_u32*)(Kb + (size_t)((kv0) + row) * 128 + csrc * 8),    \
            (lds_u32*)(&lK[buf][0][0] + (wave * 4 + j) * 512), 16, 0, 0);      \
    }

    // V staging coords: cid = wave*128 + j*64 + lane, j in {0,1}
    //   source: Vb[vd][kv0 + sck*8 .. +7]   (b128)
    //   dest:   lV[buf][vd][kva], lV[buf][vd][kva+8]  (2x b64)
    int vdj[2], vsk[2], vka[2];
#pragma unroll
    for (int j = 0; j < 2; ++j) {
        int cid = wave * 128 + j * 64 + lane;
        vdj[j] = cid >> 3;
        int sck = cid & 7;
        vsk[j] = sck * 8;
        vka[j] = (sck >> 2) * 32 + (sck & 1) * 16 + ((sck >> 1) & 1) * 4;
    }

#define LOAD_V(kv0)                                                            \
    _Pragma("unroll")                                                          \
    for (int j = 0; j < 2; ++j)                                                \
        vreg[j] = *(const uint4*)(Vb + (size_t)vdj[j] * 1024 + (kv0) + vsk[j]);
#define WRITE_V(buf)                                                           \
    _Pragma("unroll")                                                          \
    for (int j = 0; j < 2; ++j) {                                              \
        *(uint2*)&lV[buf][vdj[j]][vka[j]]     = make_uint2(vreg[j].x, vreg[j].y);\
        *(uint2*)&lV[buf][vdj[j]][vka[j] + 8] = make_uint2(vreg[j].z, vreg[j].w);\
    }

    // Q B-fragments for this wave's 16 q-rows (n=col, k=f*32+quad*8+j)
    bf16x8 qb[4];
    {
        const bf16* qrow = Qb + (size_t)(qt * 64 + wave * 16 + col) * 128;
#pragma unroll
        for (int f = 0; f < 4; ++f) qb[f] = *(const bf16x8*)(qrow + f * 32 + quad * 8);
    }

    f32x4 o[4];
#pragma unroll
    for (int vt = 0; vt < 4; ++vt) o[vt] = f32x4{0.f, 0.f, 0.f, 0.f};
    float lsum = 0.f;

    uint4 vreg[2];
    STAGE_K(0, 0)
    LOAD_V(0)
    WRITE_V(0)

    for (int it = 0; it < 16; ++it) {
        const int cur = it & 1, nxt = cur ^ 1;
        __syncthreads();
        if (it < 15) {
            const int kv1 = (it + 1) * 64;
            STAGE_K(nxt, kv1)
            LOAD_V(kv1)
        }

        // S^T = K * Q^T : A-frag = K rows (m = kv_local = t*16+col)
        f32x4 st[4];
#pragma unroll
        for (int t = 0; t < 4; ++t) st[t] = f32x4{0.f, 0.f, 0.f, 0.f};
#pragma unroll
        for (int t = 0; t < 4; ++t)
#pragma unroll
            for (int f = 0; f < 4; ++f) {
                bf16x8 kf = *(const bf16x8*)&lK[cur][t * 16 + col][((f * 4 + quad) ^ sw) * 8];
                st[t] = MFMA(kf, qb[f], st[t]);
            }

        // p = exp2(s); pack into PV B-fragments (kv-interleave by register naming)
        bf16x8 pbf[2];
#pragma unroll
        for (int c = 0; c < 2; ++c) {
#pragma unroll
            for (int r = 0; r < 4; ++r) {
                float p0 = exp2f(st[2 * c][r]);
                float p1 = exp2f(st[2 * c + 1][r]);
                lsum += p0 + p1;
                pbf[c][r]     = (bf16)p0;
                pbf[c][4 + r] = (bf16)p1;
            }
        }

        // O^T += V^T * P^T ; V fragment = ONE b128 from sigma-permuted tile
#pragma unroll
        for (int c = 0; c < 2; ++c)
#pragma unroll
            for (int vt = 0; vt < 4; ++vt) {
                bf16x8 vf = *(const bf16x8*)&lV[cur][vt * 16 + col][c * 32 + quad * 8];
                o[vt] = MFMA(vf, pbf[c], o[vt]);
            }

        if (it < 15) WRITE_V(nxt)
    }

    float l = lsum;
    l += __shfl_xor(l, 16, 64);
    l += __shfl_xor(l, 32, 64);
    const float inv = 1.f / l;

    const int qrow = qt * 64 + wave * 16 + col;
    bf16* dst = attn_out + ((size_t)b * 1024 + qrow) * 768 + h * 64;
#pragma unroll
    for (int vt = 0; vt < 4; ++vt) {
        bf16x4v pk;
#pragma unroll
        for (int r = 0; r < 4; ++r) pk[r] = (bf16)(o[vt][r] * inv);
        *(bf16x4v*)(dst + vt * 16 + quad * 4) = pk;
    }
#undef STAGE_K
#undef LOAD_V
#undef WRITE_V
}

// ---------------------------------------------------------------------------
// Out projection: out[4096][768] = aout @ woutT^T + bias (fp32 out)
// 64m x 64n tiles -> 1D grid 768 (3 blocks/CU vs 1.5 at 128x64), glds
// double-buffered, XCD-aware (each XCD owns 12bx x 8by).
// ---------------------------------------------------------------------------
__launch_bounds__(256, 3)
__global__ void k_gemm_out(const bf16* __restrict__ aout, const bf16* __restrict__ woutT,
                           const float* __restrict__ bias, float* __restrict__ out) {
    __shared__ bf16 lA[2][64][32];
    __shared__ bf16 lB[2][64][32];

    const int tid  = threadIdx.x;
    const int lane = tid & 63, wave = tid >> 6;
    const int quad = lane >> 4, col = lane & 15;
    const int sw2  = (col >> 1) & 3;
    const int wm = (wave >> 1) * 32, wn = (wave & 1) * 32;

    const int fid = blockIdx.x;
    const int xcd = fid & 7, s = fid >> 3;     // s in [0,96)
    const int bx = s % 12;                     // [0,12)
    const int by = xcd * 8 + s / 12;           // [0,64)

    const int mBase = by * 64, nBase = bx * 64;

    const bf16* Ap = aout  + (size_t)mBase * 768;
    const bf16* Bp = woutT + (size_t)nBase * 768;

#define STAGE_O(buf, k0)                                                        \
    {                                                                           \
        int idx = wave * 64 + lane;                                             \
        int row = idx >> 2, c = (idx & 3) ^ ((row >> 1) & 3);                   \
        __builtin_amdgcn_global_load_lds(                                       \
            (const glob_u32*)(Ap + (size_t)row * 768 + (k0) + c * 8),           \
            (lds_u32*)((char*)&lA[buf][0][0] + wave * 1024), 16, 0, 0);         \
        __builtin_amdgcn_global_load_lds(                                       \
            (const glob_u32*)(Bp + (size_t)row * 768 + (k0) + c * 8),           \
            (lds_u32*)((char*)&lB[buf][0][0] + wave * 1024), 16, 0, 0);         \
    }

    f32x4 acc[2][2];
#pragma unroll
    for (int mi = 0; mi < 2; ++mi)
#pragma unroll
        for (int ni = 0; ni < 2; ++ni) acc[mi][ni] = f32x4{0.f, 0.f, 0.f, 0.f};

    STAGE_O(0, 0)
    for (int it = 0; it < 24; ++it) {
        const int cur = it & 1, nxt = cur ^ 1;
        __syncthreads();
        if (it < 23) STAGE_O(nxt, (it + 1) * 32)

        bf16x8 af[2], bfg[2];
#pragma unroll
        for (int mi = 0; mi < 2; ++mi)
            af[mi]  = *(const bf16x8*)&lA[cur][wm + mi * 16 + col][(quad ^ sw2) * 8];
#pragma unroll
        for (int ni = 0; ni < 2; ++ni)
            bfg[ni] = *(const bf16x8*)&lB[cur][wn + ni * 16 + col][(quad ^ sw2) * 8];
#pragma unroll
        for (int mi = 0; mi < 2; ++mi)
#pragma unroll
            for (int ni = 0; ni < 2; ++ni)
                acc[mi][ni] = MFMA(af[mi], bfg[ni], acc[mi][ni]);
    }
#undef STAGE_O

#pragma unroll
    for (int mi = 0; mi < 2; ++mi)
#pragma unroll
        for (int ni = 0; ni < 2; ++ni)
#pragma unroll
            for (int r = 0; r < 4; ++r) {
                int m = mBase + wm + mi * 16 + quad * 4 + r;
                int n = nBase + wn + ni * 16 + col;
                out[(size_t)m * 768 + n] = acc[mi][ni][r] + bias[n];
            }
}

// ---------------------------------------------------------------------------
// Workspace layout (bytes): total 57409536 B
// ---------------------------------------------------------------------------
extern "C" void kernel_launch(void* const* d_in, const int* in_sizes, int n_in,
                              void* d_out, int out_size, void* d_ws, size_t ws_size,
                              hipStream_t stream) {
    const float* x        = (const float*)d_in[0];
    const float* pos      = (const float*)d_in[1];
    const float* w_qkv    = (const float*)d_in[2];
    const float* w_qk_pos = (const float*)d_in[3];
    const float* w_out    = (const float*)d_in[4];
    const float* b_out    = (const float*)d_in[5];
    float* out = (float*)d_out;

    char* ws = (char*)d_ws;
    bf16* xb      = (bf16*)(ws);
    bf16* posb    = (bf16*)(ws + 6291456);
    bf16* wqkvT   = (bf16*)(ws + 12582912);
    bf16* wqkposT = (bf16*)(ws + 16121856);
    bf16* woutT   = (bf16*)(ws + 18481152);
    bf16* qcat    = (bf16*)(ws + 19660800);
    bf16* kcat    = (bf16*)(ws + 32243712);
    bf16* vT      = (bf16*)(ws + 44826624);
    bf16* aout    = (bf16*)(ws + 51118080);

    k_prep<<<9600, 256, 0, stream>>>(x, pos, w_qkv, w_qk_pos, w_out,
                                     xb, posb, wqkvT, wqkposT, woutT);
    k_gemm12<<<960, 256, 0, stream>>>(xb, posb, wqkvT, wqkposT, qcat, kcat, vT);
    k_attn<<<768, 256, 0, stream>>>(qcat, kcat, vT, aout);
    k_gemm_out<<<768, 256, 0, stream>>>(aout, woutT, b_out, out);
}